// Round 9
// baseline (81.906 us; speedup 1.0000x reference)
//
#include <hip/hip_runtime.h>
#include <math.h>

#define NT 512

// 9-shift sliding-dot body. R0 receives the fresh ypad[j+C]; R1..R8 hold
// ypad[j+C-1..8] via static register rotation (no movs).
#define BODYS(J, R0,R1,R2,R3,R4,R5,R6,R7,R8) { \
    const double wv = wdBuf[(J) * 64 + hh]; \
    R0 = ypad[(J) + C]; \
    d0 = fma(wv, R0, d0); d1 = fma(wv, R1, d1); d2 = fma(wv, R2, d2); \
    d3 = fma(wv, R3, d3); d4 = fma(wv, R4, d4); d5 = fma(wv, R5, d5); \
    d6 = fma(wv, R6, d6); d7 = fma(wv, R7, d7); d8 = fma(wv, R8, d8); \
    ssq = fma(wv, wv, ssq); }

#define BODYN(J, R0,R1,R2,R3,R4,R5,R6,R7,R8) { \
    const double wv = wdBuf[(J) * 64 + hh]; \
    R0 = ypad[(J) + C]; \
    d0 = fma(wv, R0, d0); d1 = fma(wv, R1, d1); d2 = fma(wv, R2, d2); \
    d3 = fma(wv, R3, d3); d4 = fma(wv, R4, d4); d5 = fma(wv, R5, d5); \
    d6 = fma(wv, R6, d6); d7 = fma(wv, R7, d7); d8 = fma(wv, R8, d8); }

// Indirection so ROTk expands to 9 args BEFORE BODY* arity-matching.
#define BS(J, R) BODYS(J, R)
#define BN(J, R) BODYN(J, R)

#define ROT0 q0,q1,q2,q3,q4,q5,q6,q7,q8
#define ROT1 q8,q0,q1,q2,q3,q4,q5,q6,q7
#define ROT2 q7,q8,q0,q1,q2,q3,q4,q5,q6
#define ROT3 q6,q7,q8,q0,q1,q2,q3,q4,q5
#define ROT4 q5,q6,q7,q8,q0,q1,q2,q3,q4
#define ROT5 q4,q5,q6,q7,q8,q0,q1,q2,q3
#define ROT6 q3,q4,q5,q6,q7,q8,q0,q1,q2
#define ROT7 q2,q3,q4,q5,q6,q7,q8,q0,q1
#define ROT8 q1,q2,q3,q4,q5,q6,q7,q8,q0

#define PROLOG(JB) { \
    q1 = ypad[(JB) + C - 1]; q2 = ypad[(JB) + C - 2]; \
    q3 = ypad[(JB) + C - 3]; q4 = ypad[(JB) + C - 4]; \
    q5 = ypad[(JB) + C - 5]; q6 = ypad[(JB) + C - 6]; \
    q7 = ypad[(JB) + C - 7]; q8 = ypad[(JB) + C - 8]; }

// Fused: grid 1280 = (bt = bx/5, theta t5 = bx%5). 8 waves; lane = channel.
// Wave w owns strips {w, w+8} (9 shifts each): perfectly balanced.
// Per-bt election (atomic) -> 5th finisher merges + epilogue for that bt;
// global election (256) -> last merger reduces the loss.
__global__ __launch_bounds__(NT) void argaug_fused(
    const float* __restrict__ x, const float* __restrict__ y,
    const int* __restrict__ mask,
    const float* __restrict__ W1, const float* __restrict__ b1,
    const float* __restrict__ W2, const float* __restrict__ b2,
    double* __restrict__ simW, int* __restrict__ SwG,
    double* __restrict__ psum, double* __restrict__ pcnt,
    int* __restrict__ cnt_bt, int* __restrict__ cnt_all,
    float* out)
{
    __shared__ double wdBuf[76 * 64];   // 38912 B; aliased by reduce/merge bufs
    __shared__ double ypad[80];
    __shared__ float  sxy[64];          // x during fc1, y during merge
    __shared__ float  sh[64], sb1[64];
    __shared__ int    eflag[2];

    double* rsimQ = wdBuf;                      // [8*64] aliased (barrier-separated)
    int*    ridxB = (int*)(wdBuf + 512);

    const int tid = threadIdx.x;
    const int bx  = blockIdx.x;
    const int bt  = bx / 5;
    const int t5  = bx % 5;
    const int hh  = tid & 63;
    const int sg  = tid >> 6;

    const double theta = (t5 == 4) ? 1.2 : (0.8 + (double)t5 * ((1.2 - 0.8) / 4.0));
    const int L = (int)floor(64.0 * theta);   // {51,57,64,70,76}
    const int S = L + 63;
    const double rcp = 64.0 / (double)L;

    if (tid < 64) {
        sxy[tid] = x[bt * 64 + tid];
        sb1[tid] = b1[tid];
    } else if (tid >= 128 && tid < 208) {
        const int p = tid - 128;
        ypad[p] = (p >= 8 && p < 72) ? (double)y[bt * 64 + p - 8] : 0.0;
    }
    __syncthreads();

    if (tid < 64) {
        float acc = 0.0f;
        const float* w1r = W1 + tid * 64;
        for (int i = 0; i < 64; ++i) acc = fmaf(sxy[i], w1r[i], acc);
        acc += sb1[tid];
        sh[tid] = acc * (float)mask[bt * 64 + tid];
    }
    __syncthreads();

    // Phase A: wd[j][h] = (f64)(sh[h]*W2[src(j)][h] + b2[src(j)])
    for (int k = tid; k < L * 64; k += NT) {
        const int j = k >> 6, h = k & 63;
        int sj = (int)floor((double)j * rcp);
        if (sj > 63) sj = 63;
        wdBuf[k] = (double)fmaf(sh[h], W2[sj * 64 + h], b2[sj]);
    }
    __syncthreads();

    double bN = -1.0, bD = 0.0; int bi = 0x7fffffff;
    #pragma unroll 1
    for (int pp = 0; pp < 2; ++pp) {
        const int s_first = 9 * (sg + 8 * pp);
        if (s_first >= S) continue;
        const int jstart = (s_first > 63) ? (s_first - 63) : 0;
        const int jmid   = (s_first < L - 1) ? s_first : (L - 1);
        const int jend   = (s_first + 8 < L - 1) ? (s_first + 8) : (L - 1);
        const int C      = 71 - s_first;

        double d0=0,d1=0,d2=0,d3=0,d4=0,d5=0,d6=0,d7=0,d8=0,ssq=0;
        double q0=0,q1,q2,q3,q4,q5,q6,q7,q8;

        // Segment A: [jstart..jmid], with ss (ascending, same accum order as before)
        int j = jstart;
        PROLOG(j)
        const int endA = jmid + 1;
        while (j + 9 <= endA) {
            BS(j+0, ROT0) BS(j+1, ROT1) BS(j+2, ROT2)
            BS(j+3, ROT3) BS(j+4, ROT4) BS(j+5, ROT5)
            BS(j+6, ROT6) BS(j+7, ROT7) BS(j+8, ROT8)
            j += 9;
        }
        const int remA = endA - j;   // 0..8, phase resets to 0
        if (remA > 0) { BS(j+0, ROT0) }
        if (remA > 1) { BS(j+1, ROT1) }
        if (remA > 2) { BS(j+2, ROT2) }
        if (remA > 3) { BS(j+3, ROT3) }
        if (remA > 4) { BS(j+4, ROT4) }
        if (remA > 5) { BS(j+5, ROT5) }
        if (remA > 6) { BS(j+6, ROT6) }
        if (remA > 7) { BS(j+7, ROT7) }

        // Segment B: (jmid..jend], no ss, <=8 bodies; fresh prologue resets phase
        const int lenB = jend - jmid;
        if (lenB > 0) {
            j = jmid + 1;
            PROLOG(j)
            { BN(j+0, ROT0) }
            if (lenB > 1) { BN(j+1, ROT1) }
            if (lenB > 2) { BN(j+2, ROT2) }
            if (lenB > 3) { BN(j+3, ROT3) }
            if (lenB > 4) { BN(j+4, ROT4) }
            if (lenB > 5) { BN(j+5, ROT5) }
            if (lenB > 6) { BN(j+6, ROT6) }
            if (lenB > 7) { BN(j+7, ROT7) }
        }

        const int kmax = (S - s_first < 9) ? (S - s_first) : 9;
        double ss = ssq;
        #define SSUP(kk) { \
            const int jh = s_first + kk; \
            const int jl = jh - 64; \
            if (jh <= L - 1) { const double w = wdBuf[jh * 64 + hh]; ss = fma(w,  w, ss); } \
            if (jl >= 0)     { const double w = wdBuf[jl * 64 + hh]; ss = fma(-w, w, ss); } }
        #define EVALK(kk, dk) { \
            double pn, pd; \
            if (ss > 0.0) { pn = dk * fabs(dk); pd = ss; } \
            else          { pn = 0.0;           pd = 1.0; } \
            if (pn * bD > bN * pd) { bN = pn; bD = pd; bi = s_first + kk; } }
        EVALK(0, d0)
        if (1 < kmax) { SSUP(1) EVALK(1, d1) }
        if (2 < kmax) { SSUP(2) EVALK(2, d2) }
        if (3 < kmax) { SSUP(3) EVALK(3, d3) }
        if (4 < kmax) { SSUP(4) EVALK(4, d4) }
        if (5 < kmax) { SSUP(5) EVALK(5, d5) }
        if (6 < kmax) { SSUP(6) EVALK(6, d6) }
        if (7 < kmax) { SSUP(7) EVALK(7, d7) }
        if (8 < kmax) { SSUP(8) EVALK(8, d8) }
        #undef SSUP
        #undef EVALK
    }

    __syncthreads();                 // wdBuf reads done before alias writes
    // quotient is monotone in sim; bD>0 always (first EVALK always accepts)
    rsimQ[sg * 64 + hh] = bN / bD;
    ridxB[sg * 64 + hh] = bi;
    __syncthreads();
    if (tid < 64) {
        double m = rsimQ[tid]; int mi = ridxB[tid];
        for (int g = 1; g < 8; ++g) {
            const double v = rsimQ[g * 64 + tid]; const int vi = ridxB[g * 64 + tid];
            if (v > m || (v == m && vi < mi)) { m = v; mi = vi; }
        }
        const int o = (t5 * 256 + bt) * 64 + tid;
        simW[o] = m;
        SwG[o]  = mi;
    }
    __syncthreads();

    // ---- per-bt election: 5th finisher merges ----
    if (tid == 0) {
        __threadfence();
        const int old = atomicAdd(&cnt_bt[bt], 1);
        if (old == 4) { __threadfence(); eflag[0] = 1; } else eflag[0] = 0;
    }
    __syncthreads();
    if (eflag[0] == 0) return;

    // merge-phase LDS aliases (rsimQ/ridxB dead)
    double* mpart = wdBuf;                 // [8][64]
    double* mssum = wdBuf + 512;           // [64]
    double* msu   = wdBuf + 576;           // [64]
    int*    mbS   = (int*)(wdBuf + 640);   // [64]
    int*    mbT   = mbS + 64;              // [64]

    if (tid < 64) {
        sxy[tid] = y[bt * 64 + tid];       // sy now
        // merge across thetas: ascending t5, strictly greater replaces
        int o0 = bt * 64 + tid;
        double mN = simW[o0]; int mS = SwG[o0], mT = 0;
        for (int t = 1; t < 5; ++t) {
            const int o = (t * 256 + bt) * 64 + tid;
            const double v = simW[o];
            if (v > mN) { mN = v; mS = SwG[o]; mT = t; }
        }
        mbS[tid] = mS; mbT[tid] = mT;
    }
    __syncthreads();

    // ssum[i] = sum over h of chosen window value at element i (8 groups x 8 h)
    {
        const int g = sg, i = hh;
        double acc = 0.0;
        for (int q = 0; q < 8; ++q) {
            const int h = g * 8 + q;
            const int t = mbT[h];
            const double th2 = (t == 4) ? 1.2 : (0.8 + (double)t * ((1.2 - 0.8) / 4.0));
            const int Lh = (int)floor(64.0 * th2);
            const double rc = 64.0 / (double)Lh;
            const int jj = mbS[h] - 63 + i;
            if (jj >= 0 && jj < Lh) {
                int sj = (int)floor((double)jj * rc);
                if (sj > 63) sj = 63;
                acc += (double)fmaf(sh[h], W2[sj * 64 + h], b2[sj]);
            }
        }
        mpart[g * 64 + i] = acc;
    }
    __syncthreads();
    if (tid < 64) {
        double s0 = 0.0;
        for (int g = 0; g < 8; ++g) s0 += mpart[g * 64 + tid];
        mssum[tid] = s0;
    }
    __syncthreads();
    // u = W1 * ssum + 64*b1
    {
        const int g = sg, i = hh, base = g * 8;
        double acc = 0.0;
        for (int q = 0; q < 8; ++q)
            acc += (double)W1[i * 64 + base + q] * mssum[base + q];
        mpart[g * 64 + i] = acc;
    }
    __syncthreads();
    if (tid < 64) {
        double s0 = 64.0 * (double)sb1[tid];
        for (int g = 0; g < 8; ++g) s0 += mpart[g * 64 + tid];
        msu[tid] = s0;
    }
    __syncthreads();
    // v = W2 * u + 64*b2
    {
        const int g = sg, i = hh, base = g * 8;
        double acc = 0.0;
        for (int q = 0; q < 8; ++q)
            acc += (double)W2[i * 64 + base + q] * msu[base + q];
        mpart[g * 64 + i] = acc;
    }
    __syncthreads();
    if (tid < 64) {
        double v = 64.0 * (double)b2[tid];
        for (int g = 0; g < 8; ++g) v += mpart[g * 64 + tid];
        const float outf = (float)v;
        out[1 + bt * 64 + tid] = outf;     // xf
        const float yv = sxy[tid];
        double pl = 0.0, pc = 0.0;
        if (yv != 0.0f) {
            const float d = outf - yv;
            pl = (double)(d * d);
            pc = 1.0;
        }
        for (int o = 32; o > 0; o >>= 1) {
            pl += __shfl_down(pl, o, 64);
            pc += __shfl_down(pc, o, 64);
        }
        if (tid == 0) { psum[bt] = pl; pcnt[bt] = pc; }
    }
    __syncthreads();

    // ---- global election: last merger reduces the loss ----
    if (tid == 0) {
        __threadfence();
        const int old = atomicAdd(cnt_all, 1);
        if (old == 255) { __threadfence(); eflag[1] = 1; } else eflag[1] = 0;
    }
    __syncthreads();
    if (eflag[1] == 0) return;

    if (tid < 64) {
        double a = 0.0, c = 0.0;
        for (int r = 0; r < 4; ++r) {
            a += psum[tid * 4 + r];
            c += pcnt[tid * 4 + r];
        }
        for (int o = 32; o > 0; o >>= 1) {
            a += __shfl_down(a, o, 64);
            c += __shfl_down(c, o, 64);
        }
        if (tid == 0) out[0] = (float)(a / c);
    }
}

extern "C" void kernel_launch(void* const* d_in, const int* in_sizes, int n_in,
                              void* d_out, int out_size, void* d_ws, size_t ws_size,
                              hipStream_t stream) {
    const float* x    = (const float*)d_in[0];
    const float* y    = (const float*)d_in[1];
    const int*   mask = (const int*)d_in[2];
    const float* W1   = (const float*)d_in[3];
    const float* b1   = (const float*)d_in[4];
    const float* W2   = (const float*)d_in[5];
    const float* b2   = (const float*)d_in[6];
    float* out = (float*)d_out;

    char* ws = (char*)d_ws;
    double* simW   = (double*)(ws);            // 5*256*64 f64 = 655360 B
    int*    SwG    = (int*)(ws + 655360);      // 327680 B
    double* psum   = (double*)(ws + 983040);   // 2048 B
    double* pcnt   = (double*)(ws + 985088);   // 2048 B
    int*    cnt_bt = (int*)(ws + 987136);      // 256 ints
    int*    cnt_all= cnt_bt + 256;             // 1 int

    hipMemsetAsync(ws + 987136, 0, 257 * sizeof(int), stream);
    argaug_fused<<<1280, NT, 0, stream>>>(x, y, mask, W1, b1, W2, b2,
                                          simW, SwG, psum, pcnt,
                                          cnt_bt, cnt_all, out);
}

// Round 10
// 76.280 us; speedup vs baseline: 1.0738x; 1.0738x over previous
//
#include <hip/hip_runtime.h>
#include <math.h>

#define NT 512
#define NWAVE 8

// Fused: grid 1280 = (theta t5 = bx>>8) x (bt = bx&255). 8 waves; lane =
// channel hh; wave w owns strips {w, w+8} (9 shifts each): span(w)+span(w+8)
// == L exactly -> perfect balance. Window values stored as f32 in LDS and
// widened (exactly) to f64 at use -- decision math bitwise-identical to the
// f64-buffer version. Per-bt election -> 5th finisher merges + epilogue;
// global election -> last merger reduces the loss.
__global__ __launch_bounds__(NT) void argaug_fused(
    const float* __restrict__ x, const float* __restrict__ y,
    const int* __restrict__ mask,
    const float* __restrict__ W1, const float* __restrict__ b1,
    const float* __restrict__ W2, const float* __restrict__ b2,
    double* __restrict__ simW, int* __restrict__ SwG,
    double* __restrict__ psum, double* __restrict__ pcnt,
    int* __restrict__ cnt_bt, int* __restrict__ cnt_all,
    float* out)
{
    __shared__ float  wdBuf[76 * 64];          // f32 window values (19456 B)
    __shared__ double ypad[80];                // ypad[p] = y[p-8], p in [8,71], else 0
    __shared__ float  sxy[64], sh[64], sb1[64];
    __shared__ double rbufQ[NWAVE * 64];       // per-wave best quotient; reused as mpart
    __shared__ int    ridxB[NWAVE * 64];
    __shared__ double mssum[64], msu[64];
    __shared__ int    mbS[64], mbT[64];
    __shared__ int    eflag[2];

    const int tid = threadIdx.x;
    const int bx  = blockIdx.x;
    const int bt  = bx & 255;
    const int t5  = bx >> 8;
    const int hh  = tid & 63;
    const int sg  = tid >> 6;

    const double theta = (t5 == 4) ? 1.2 : (0.8 + (double)t5 * ((1.2 - 0.8) / 4.0));
    const int L = (int)floor(64.0 * theta);   // {51,57,64,70,76}
    const int S = L + 63;
    const double rcp = 64.0 / (double)L;

    if (tid < 64) {
        sxy[tid] = x[bt * 64 + tid];
        sb1[tid] = b1[tid];
    } else if (tid >= 128 && tid < 208) {
        const int p = tid - 128;
        ypad[p] = (p >= 8 && p < 72) ? (double)y[bt * 64 + p - 8] : 0.0;
    }
    __syncthreads();

    if (tid < 64) {
        float acc = 0.0f;
        const float* w1r = W1 + tid * 64;
        for (int i = 0; i < 64; ++i) acc = fmaf(sxy[i], w1r[i], acc);
        acc += sb1[tid];
        sh[tid] = acc * (float)mask[bt * 64 + tid];
    }
    __syncthreads();

    // Phase A: wd[j][h] = sh[h]*W2[src(j)][h] + b2[src(j)]  (f32, exact widen later)
    for (int k = tid; k < L * 64; k += NT) {
        const int j = k >> 6, h = k & 63;
        int sj = (int)floor((double)j * rcp);
        if (sj > 63) sj = 63;
        wdBuf[k] = fmaf(sh[h], W2[sj * 64 + h], b2[sj]);
    }
    __syncthreads();

    double bN = -1.0, bD = 0.0; int bi = 0x7fffffff;
    #pragma unroll 2
    for (int pp = 0; pp < 2; ++pp) {
        const int s_first = 9 * (sg + 8 * pp);
        if (s_first >= S) continue;
        const int jstart = (s_first > 63) ? (s_first - 63) : 0;
        const int jmid   = (s_first < L - 1) ? s_first : (L - 1);
        const int jend   = (s_first + 8 < L - 1) ? (s_first + 8) : (L - 1);
        const int C      = 71 - s_first;      // ypad idx = j + C - k

        double d0=0,d1=0,d2=0,d3=0,d4=0,d5=0,d6=0,d7=0,d8=0,ssA=0;
        double ym1 = ypad[jstart + C - 1];
        double ym2 = ypad[jstart + C - 2];
        double ym3 = ypad[jstart + C - 3];
        double ym4 = ypad[jstart + C - 4];
        double ym5 = ypad[jstart + C - 5];
        double ym6 = ypad[jstart + C - 6];
        double ym7 = ypad[jstart + C - 7];
        double ym8 = ypad[jstart + C - 8];

        #pragma unroll 9
        for (int j = jstart; j <= jmid; ++j) {
            const double w  = (double)wdBuf[j * 64 + hh];
            const double y0 = ypad[j + C];
            d0 = fma(w, y0,  d0); d1 = fma(w, ym1, d1); d2 = fma(w, ym2, d2);
            d3 = fma(w, ym3, d3); d4 = fma(w, ym4, d4); d5 = fma(w, ym5, d5);
            d6 = fma(w, ym6, d6); d7 = fma(w, ym7, d7); d8 = fma(w, ym8, d8);
            ssA = fma(w, w, ssA);
            ym8=ym7; ym7=ym6; ym6=ym5; ym5=ym4; ym4=ym3; ym3=ym2; ym2=ym1; ym1=y0;
        }
        #pragma unroll 9
        for (int j = jmid + 1; j <= jend; ++j) {
            const double w  = (double)wdBuf[j * 64 + hh];
            const double y0 = ypad[j + C];
            d0 = fma(w, y0,  d0); d1 = fma(w, ym1, d1); d2 = fma(w, ym2, d2);
            d3 = fma(w, ym3, d3); d4 = fma(w, ym4, d4); d5 = fma(w, ym5, d5);
            d6 = fma(w, ym6, d6); d7 = fma(w, ym7, d7); d8 = fma(w, ym8, d8);
            ym8=ym7; ym7=ym6; ym6=ym5; ym5=ym4; ym4=ym3; ym3=ym2; ym2=ym1; ym1=y0;
        }

        const int kmax = (S - s_first < 9) ? (S - s_first) : 9;
        double ss = ssA;
        #define SSUP(kk) { \
            const int jh = s_first + kk; \
            const int jl = jh - 64; \
            if (jh <= L - 1) { const double w = (double)wdBuf[jh * 64 + hh]; ss = fma(w,  w, ss); } \
            if (jl >= 0)     { const double w = (double)wdBuf[jl * 64 + hh]; ss = fma(-w, w, ss); } }
        #define EVALK(kk, dk) { \
            double pn, pd; \
            if (ss > 0.0) { pn = dk * fabs(dk); pd = ss; } \
            else          { pn = 0.0;           pd = 1.0; } \
            if (pn * bD > bN * pd) { bN = pn; bD = pd; bi = s_first + kk; } }
        EVALK(0, d0)
        if (1 < kmax) { SSUP(1) EVALK(1, d1) }
        if (2 < kmax) { SSUP(2) EVALK(2, d2) }
        if (3 < kmax) { SSUP(3) EVALK(3, d3) }
        if (4 < kmax) { SSUP(4) EVALK(4, d4) }
        if (5 < kmax) { SSUP(5) EVALK(5, d5) }
        if (6 < kmax) { SSUP(6) EVALK(6, d6) }
        if (7 < kmax) { SSUP(7) EVALK(7, d7) }
        if (8 < kmax) { SSUP(8) EVALK(8, d8) }
        #undef SSUP
        #undef EVALK
    }

    // quotient is monotone in sim; bD>0 always (first EVALK always accepts)
    rbufQ[sg * 64 + hh] = bN / bD;
    ridxB[sg * 64 + hh] = bi;
    __syncthreads();
    if (tid < 64) {
        // waves interleave s-order -> tie-break on smaller shift index
        // (exact ties have bitwise-equal quotients).
        double m = rbufQ[tid]; int mi = ridxB[tid];
        for (int g = 1; g < NWAVE; ++g) {
            const double v = rbufQ[g * 64 + tid]; const int vi = ridxB[g * 64 + tid];
            if (v > m || (v == m && vi < mi)) { m = v; mi = vi; }
        }
        const int o = (t5 * 256 + bt) * 64 + tid;
        simW[o] = m;
        SwG[o]  = mi;
    }
    __syncthreads();

    // ---- per-bt election: 5th finisher merges ----
    if (tid == 0) {
        __threadfence();
        const int old = atomicAdd(&cnt_bt[bt], 1);
        if (old == 4) { __threadfence(); eflag[0] = 1; } else eflag[0] = 0;
    }
    __syncthreads();
    if (eflag[0] == 0) return;

    double* mpart = rbufQ;               // reuse (barrier-separated, same type)

    if (tid < 64) {
        sxy[tid] = y[bt * 64 + tid];     // sy now
        // merge across thetas: ascending t5, strictly greater replaces
        const int o0 = bt * 64 + tid;
        double mN = simW[o0]; int mS = SwG[o0], mT = 0;
        for (int t = 1; t < 5; ++t) {
            const int o = (t * 256 + bt) * 64 + tid;
            const double v = simW[o];
            if (v > mN) { mN = v; mS = SwG[o]; mT = t; }
        }
        mbS[tid] = mS; mbT[tid] = mT;
    }
    __syncthreads();

    // ssum[i] = sum over h of chosen window value at element i (8 groups x 8 h)
    {
        const int g = sg, i = hh;
        double acc = 0.0;
        for (int q = 0; q < 8; ++q) {
            const int h = g * 8 + q;
            const int t = mbT[h];
            const double th2 = (t == 4) ? 1.2 : (0.8 + (double)t * ((1.2 - 0.8) / 4.0));
            const int Lh = (int)floor(64.0 * th2);
            const double rc = 64.0 / (double)Lh;
            const int jj = mbS[h] - 63 + i;
            if (jj >= 0 && jj < Lh) {
                int sj = (int)floor((double)jj * rc);
                if (sj > 63) sj = 63;
                acc += (double)fmaf(sh[h], W2[sj * 64 + h], b2[sj]);
            }
        }
        mpart[g * 64 + i] = acc;
    }
    __syncthreads();
    if (tid < 64) {
        double s0 = 0.0;
        for (int g = 0; g < 8; ++g) s0 += mpart[g * 64 + tid];
        mssum[tid] = s0;
    }
    __syncthreads();
    // u = W1 * ssum + 64*b1
    {
        const int g = sg, i = hh, base = g * 8;
        double acc = 0.0;
        for (int q = 0; q < 8; ++q)
            acc += (double)W1[i * 64 + base + q] * mssum[base + q];
        mpart[g * 64 + i] = acc;
    }
    __syncthreads();
    if (tid < 64) {
        double s0 = 64.0 * (double)sb1[tid];
        for (int g = 0; g < 8; ++g) s0 += mpart[g * 64 + tid];
        msu[tid] = s0;
    }
    __syncthreads();
    // v = W2 * u + 64*b2
    {
        const int g = sg, i = hh, base = g * 8;
        double acc = 0.0;
        for (int q = 0; q < 8; ++q)
            acc += (double)W2[i * 64 + base + q] * msu[base + q];
        mpart[g * 64 + i] = acc;
    }
    __syncthreads();
    if (tid < 64) {
        double v = 64.0 * (double)b2[tid];
        for (int g = 0; g < 8; ++g) v += mpart[g * 64 + tid];
        const float outf = (float)v;
        out[1 + bt * 64 + tid] = outf;     // xf
        const float yv = sxy[tid];
        double pl = 0.0, pc = 0.0;
        if (yv != 0.0f) {
            const float d = outf - yv;
            pl = (double)(d * d);
            pc = 1.0;
        }
        for (int o = 32; o > 0; o >>= 1) {
            pl += __shfl_down(pl, o, 64);
            pc += __shfl_down(pc, o, 64);
        }
        if (tid == 0) { psum[bt] = pl; pcnt[bt] = pc; }
    }
    __syncthreads();

    // ---- global election: last merger reduces the loss ----
    if (tid == 0) {
        __threadfence();
        const int old = atomicAdd(cnt_all, 1);
        if (old == 255) { __threadfence(); eflag[1] = 1; } else eflag[1] = 0;
    }
    __syncthreads();
    if (eflag[1] == 0) return;

    if (tid < 64) {
        double a = 0.0, c = 0.0;
        for (int r = 0; r < 4; ++r) {
            a += psum[tid * 4 + r];
            c += pcnt[tid * 4 + r];
        }
        for (int o = 32; o > 0; o >>= 1) {
            a += __shfl_down(a, o, 64);
            c += __shfl_down(c, o, 64);
        }
        if (tid == 0) out[0] = (float)(a / c);
    }
}

extern "C" void kernel_launch(void* const* d_in, const int* in_sizes, int n_in,
                              void* d_out, int out_size, void* d_ws, size_t ws_size,
                              hipStream_t stream) {
    const float* x    = (const float*)d_in[0];
    const float* y    = (const float*)d_in[1];
    const int*   mask = (const int*)d_in[2];
    const float* W1   = (const float*)d_in[3];
    const float* b1   = (const float*)d_in[4];
    const float* W2   = (const float*)d_in[5];
    const float* b2   = (const float*)d_in[6];
    float* out = (float*)d_out;

    char* ws = (char*)d_ws;
    double* simW   = (double*)(ws);            // 5*256*64 f64 = 655360 B
    int*    SwG    = (int*)(ws + 655360);      // 327680 B
    double* psum   = (double*)(ws + 983040);   // 2048 B
    double* pcnt   = (double*)(ws + 985088);   // 2048 B
    int*    cnt_bt = (int*)(ws + 987136);      // 256 ints
    int*    cnt_all= cnt_bt + 256;             // 1 int

    hipMemsetAsync(ws + 987136, 0, 257 * sizeof(int), stream);
    argaug_fused<<<1280, NT, 0, stream>>>(x, y, mask, W1, b1, W2, b2,
                                          simW, SwG, psum, pcnt,
                                          cnt_bt, cnt_all, out);
}

// Round 11
// 54.591 us; speedup vs baseline: 1.5004x; 1.3973x over previous
//
#include <hip/hip_runtime.h>
#include <math.h>

#define NT 512
#define NWAVE 8

// One block per bt (grid 256). 8 waves; lane = channel hh. All 5 thetas
// scanned in-block via gathers of P[o][h] = sh[h]*W2[o][h] + b2[o] (f32 LDS,
// widened exactly to f64 at use -- decision math bitwise-identical to all
// previous passing rounds). Wave w owns strips {w, w+8} (9 shifts each) per
// theta: span(w)+span(w+8) ~= L, perfectly balanced. Per-thread best carries
// packed idx = (t5<<8)|s  -> lexicographic (theta asc, s asc) tie rule.
// Epilogue (window-sum, 2 GEMVs, loss partials) runs in the same block.
__global__ __launch_bounds__(NT) void argaug_all(
    const float* __restrict__ x, const float* __restrict__ y,
    const int* __restrict__ mask,
    const float* __restrict__ W1, const float* __restrict__ b1,
    const float* __restrict__ W2, const float* __restrict__ b2,
    float* __restrict__ out, double* __restrict__ psum, double* __restrict__ pcnt)
{
    __shared__ float  P[4096];          // 16 KB: P[o*64+h]
    __shared__ double ypad[80];         // ypad[p] = y[p-8] for p in [8,71], else 0
    __shared__ float  sxy[64], sh[64], sb1[64];
    __shared__ int    ssrcAll[320];     // concatenated per-theta src*64 tables
    __shared__ double rbufN[NWAVE*64], rbufD[NWAVE*64];  // rbufN reused as mpart
    __shared__ int    ridxB[NWAVE*64];
    __shared__ double mssum[64], msu[64];
    __shared__ int    mbS[64], mbT[64];

    const int tid = threadIdx.x;
    const int bt  = blockIdx.x;
    const int hh  = tid & 63;
    const int sg  = tid >> 6;

    if (tid < 64) {
        sxy[tid] = x[bt * 64 + tid];
        sb1[tid] = b1[tid];
    } else if (tid >= 128 && tid < 208) {
        const int p = tid - 128;
        ypad[p] = (p >= 8 && p < 72) ? (double)y[bt * 64 + p - 8] : 0.0;
    }
    __syncthreads();

    if (tid < 64) {
        float acc = 0.0f;
        const float* w1r = W1 + tid * 64;
        for (int i = 0; i < 64; ++i) acc = fmaf(sxy[i], w1r[i], acc);
        acc += sb1[tid];
        sh[tid] = acc * (float)mask[bt * 64 + tid];
    }
    __syncthreads();

    // P table: P[o*64+h] = sh[h]*W2[o][h] + b2[o]  (same fmaf as before)
    for (int k = tid; k < 4096; k += NT) {
        P[k] = fmaf(sh[k & 63], W2[k], b2[k >> 6]);
    }
    // all 5 src tables (concatenated; offsets = cumsum of L)
    for (int k = tid; k < 318; k += NT) {
        int rem = k, t5 = 0;
        int L = 51;                    // Ls = {51,57,64,70,76}
        for (;;) {
            const double th = (t5 == 4) ? 1.2 : (0.8 + (double)t5 * ((1.2 - 0.8) / 4.0));
            L = (int)floor(64.0 * th);
            if (rem < L) break;
            rem -= L; ++t5;
        }
        const double rcp = 64.0 / (double)L;
        int sj = (int)floor((double)rem * rcp);
        if (sj > 63) sj = 63;
        ssrcAll[k] = sj * 64;
    }
    __syncthreads();

    // ---- scan all 5 thetas, no barriers ----
    double bN = -1.0, bD = 0.0; int bi = 0x7fffffff;
    int off = 0;
    for (int t5 = 0; t5 < 5; ++t5) {
        const double theta = (t5 == 4) ? 1.2 : (0.8 + (double)t5 * ((1.2 - 0.8) / 4.0));
        const int L = (int)floor(64.0 * theta);
        const int S = L + 63;
        const int* srcT = ssrcAll + off;
        off += L;

        #pragma unroll 2
        for (int pp = 0; pp < 2; ++pp) {
            const int s_first = 9 * (sg + 8 * pp);
            if (s_first >= S) continue;
            const int jstart = (s_first > 63) ? (s_first - 63) : 0;
            const int jmid   = (s_first < L - 1) ? s_first : (L - 1);
            const int jend   = (s_first + 8 < L - 1) ? (s_first + 8) : (L - 1);
            const int C      = 71 - s_first;      // ypad idx = j + C - k

            double d0=0,d1=0,d2=0,d3=0,d4=0,d5=0,d6=0,d7=0,d8=0,ssA=0;
            double ym1 = ypad[jstart + C - 1];
            double ym2 = ypad[jstart + C - 2];
            double ym3 = ypad[jstart + C - 3];
            double ym4 = ypad[jstart + C - 4];
            double ym5 = ypad[jstart + C - 5];
            double ym6 = ypad[jstart + C - 6];
            double ym7 = ypad[jstart + C - 7];
            double ym8 = ypad[jstart + C - 8];

            #pragma unroll 9
            for (int j = jstart; j <= jmid; ++j) {
                const double w  = (double)P[srcT[j] + hh];
                const double y0 = ypad[j + C];
                d0 = fma(w, y0,  d0); d1 = fma(w, ym1, d1); d2 = fma(w, ym2, d2);
                d3 = fma(w, ym3, d3); d4 = fma(w, ym4, d4); d5 = fma(w, ym5, d5);
                d6 = fma(w, ym6, d6); d7 = fma(w, ym7, d7); d8 = fma(w, ym8, d8);
                ssA = fma(w, w, ssA);
                ym8=ym7; ym7=ym6; ym6=ym5; ym5=ym4; ym4=ym3; ym3=ym2; ym2=ym1; ym1=y0;
            }
            #pragma unroll 9
            for (int j = jmid + 1; j <= jend; ++j) {
                const double w  = (double)P[srcT[j] + hh];
                const double y0 = ypad[j + C];
                d0 = fma(w, y0,  d0); d1 = fma(w, ym1, d1); d2 = fma(w, ym2, d2);
                d3 = fma(w, ym3, d3); d4 = fma(w, ym4, d4); d5 = fma(w, ym5, d5);
                d6 = fma(w, ym6, d6); d7 = fma(w, ym7, d7); d8 = fma(w, ym8, d8);
                ym8=ym7; ym7=ym6; ym6=ym5; ym5=ym4; ym4=ym3; ym3=ym2; ym2=ym1; ym1=y0;
            }

            const int kmax = (S - s_first < 9) ? (S - s_first) : 9;
            double ss = ssA;
            #define SSUP(kk) { \
                const int jh = s_first + kk; \
                const int jl = jh - 64; \
                if (jh <= L - 1) { const double w = (double)P[srcT[jh] + hh]; ss = fma(w,  w, ss); } \
                if (jl >= 0)     { const double w = (double)P[srcT[jl] + hh]; ss = fma(-w, w, ss); } }
            #define EVALK(kk, dk) { \
                double pn, pd; \
                if (ss > 0.0) { pn = dk * fabs(dk); pd = ss; } \
                else          { pn = 0.0;           pd = 1.0; } \
                if (pn * bD > bN * pd) { bN = pn; bD = pd; bi = (t5 << 8) | (s_first + kk); } }
            EVALK(0, d0)
            if (1 < kmax) { SSUP(1) EVALK(1, d1) }
            if (2 < kmax) { SSUP(2) EVALK(2, d2) }
            if (3 < kmax) { SSUP(3) EVALK(3, d3) }
            if (4 < kmax) { SSUP(4) EVALK(4, d4) }
            if (5 < kmax) { SSUP(5) EVALK(5, d5) }
            if (6 < kmax) { SSUP(6) EVALK(6, d6) }
            if (7 < kmax) { SSUP(7) EVALK(7, d7) }
            if (8 < kmax) { SSUP(8) EVALK(8, d8) }
            #undef SSUP
            #undef EVALK
        }
    }

    rbufN[sg * 64 + hh] = bN;
    rbufD[sg * 64 + hh] = bD;
    ridxB[sg * 64 + hh] = bi;
    __syncthreads();
    if (tid < 64) {
        // candidates within a thread arrive (theta asc, s asc) -> strict >
        // kept first; across waves, packed idx gives (theta asc, s asc).
        double mN = -1.0, mD = 0.0; int mi = 0x7fffffff;
        for (int g = 0; g < NWAVE; ++g) {
            const double vN = rbufN[g * 64 + tid];
            const double vD = rbufD[g * 64 + tid];
            const int    vi = ridxB[g * 64 + tid];
            const double a = vN * mD, b = mN * vD;
            if (a > b || (a == b && vi < mi)) { mN = vN; mD = vD; mi = vi; }
        }
        mbS[tid] = mi & 255;
        mbT[tid] = mi >> 8;
        sxy[tid] = y[bt * 64 + tid];       // sy for the loss
    }
    __syncthreads();

    double* mpart = rbufN;                 // reuse (barrier-separated)

    // ssum[i] = sum over h of chosen window value at element i (8 groups x 8 h)
    {
        const int g = sg, i = hh;
        double acc = 0.0;
        for (int q = 0; q < 8; ++q) {
            const int h = g * 8 + q;
            const int t = mbT[h];
            const double th2 = (t == 4) ? 1.2 : (0.8 + (double)t * ((1.2 - 0.8) / 4.0));
            const int Lh = (int)floor(64.0 * th2);
            const double rc = 64.0 / (double)Lh;
            const int jj = mbS[h] - 63 + i;
            if (jj >= 0 && jj < Lh) {
                int sj = (int)floor((double)jj * rc);
                if (sj > 63) sj = 63;
                acc += (double)P[sj * 64 + h];   // == fmaf(sh[h],W2[sj][h],b2[sj])
            }
        }
        mpart[g * 64 + i] = acc;
    }
    __syncthreads();
    if (tid < 64) {
        double s0 = 0.0;
        for (int g = 0; g < 8; ++g) s0 += mpart[g * 64 + tid];
        mssum[tid] = s0;
    }
    __syncthreads();
    // u = W1 * ssum + 64*b1
    {
        const int g = sg, i = hh, base = g * 8;
        double acc = 0.0;
        for (int q = 0; q < 8; ++q)
            acc += (double)W1[i * 64 + base + q] * mssum[base + q];
        mpart[g * 64 + i] = acc;
    }
    __syncthreads();
    if (tid < 64) {
        double s0 = 64.0 * (double)sb1[tid];
        for (int g = 0; g < 8; ++g) s0 += mpart[g * 64 + tid];
        msu[tid] = s0;
    }
    __syncthreads();
    // v = W2 * u + 64*b2
    {
        const int g = sg, i = hh, base = g * 8;
        double acc = 0.0;
        for (int q = 0; q < 8; ++q)
            acc += (double)W2[i * 64 + base + q] * msu[base + q];
        mpart[g * 64 + i] = acc;
    }
    __syncthreads();
    if (tid < 64) {
        double v = 64.0 * (double)b2[tid];
        for (int g = 0; g < 8; ++g) v += mpart[g * 64 + tid];
        const float outf = (float)v;
        out[1 + bt * 64 + tid] = outf;     // xf
        const float yv = sxy[tid];
        double pl = 0.0, pc = 0.0;
        if (yv != 0.0f) {
            const float d = outf - yv;
            pl = (double)(d * d);
            pc = 1.0;
        }
        for (int o = 32; o > 0; o >>= 1) {
            pl += __shfl_down(pl, o, 64);
            pc += __shfl_down(pc, o, 64);
        }
        if (tid == 0) { psum[bt] = pl; pcnt[bt] = pc; }
    }
}

__global__ __launch_bounds__(256) void finalize_loss(
    const double* __restrict__ psum, const double* __restrict__ pcnt,
    float* __restrict__ out)
{
    __shared__ double a[256], c[256];
    const int t = threadIdx.x;
    a[t] = psum[t];
    c[t] = pcnt[t];
    __syncthreads();
    for (int s = 128; s > 0; s >>= 1) {
        if (t < s) { a[t] += a[t + s]; c[t] += c[t + s]; }
        __syncthreads();
    }
    if (t == 0) out[0] = (float)(a[0] / c[0]);
}

extern "C" void kernel_launch(void* const* d_in, const int* in_sizes, int n_in,
                              void* d_out, int out_size, void* d_ws, size_t ws_size,
                              hipStream_t stream) {
    const float* x    = (const float*)d_in[0];
    const float* y    = (const float*)d_in[1];
    const int*   mask = (const int*)d_in[2];
    const float* W1   = (const float*)d_in[3];
    const float* b1   = (const float*)d_in[4];
    const float* W2   = (const float*)d_in[5];
    const float* b2   = (const float*)d_in[6];
    float* out = (float*)d_out;

    double* psum = (double*)d_ws;
    double* pcnt = psum + 256;

    argaug_all<<<256, NT, 0, stream>>>(x, y, mask, W1, b1, W2, b2,
                                       out, psum, pcnt);
    finalize_loss<<<1, 256, 0, stream>>>(psum, pcnt, out);
}

// Round 12
// 45.280 us; speedup vs baseline: 1.8089x; 1.2056x over previous
//
#include <hip/hip_runtime.h>
#include <math.h>

#define NT 1024
#define NWAVE 16

// One block per bt (grid 256), 16 waves = 4/SIMD. Lane = channel hh.
// Wave group 0 (waves 0-7) scans thetas {0,1,2}; group 1 (waves 8-15) scans
// {3,4}. Within a group, wave w owns strips {w, w+8} (9 shifts each) per
// theta -- perfectly balanced. All thetas gather from one table
// P[o][h] = sh[h]*W2[o][h] + b2[o] (f32 LDS, widened exactly to f64 at use;
// decision math bitwise-identical to prior passing rounds). Per-thread best
// carries packed idx = (t5<<8)|s -> lexicographic (theta asc, s asc) ties.
// Epilogue runs in the same block; its gathers use global W2/b2 (same bits,
// no LDS bank conflicts).
__global__ __launch_bounds__(NT) void argaug_all(
    const float* __restrict__ x, const float* __restrict__ y,
    const int* __restrict__ mask,
    const float* __restrict__ W1, const float* __restrict__ b1,
    const float* __restrict__ W2, const float* __restrict__ b2,
    float* __restrict__ out, double* __restrict__ psum, double* __restrict__ pcnt)
{
    __shared__ float  P[4096];          // 16 KB: P[o*64+h]
    __shared__ double ypad[80];         // ypad[p] = y[p-8] for p in [8,71], else 0
    __shared__ float  sxy[64], sh[64], sb1[64];
    __shared__ int    ssrcAll[320];     // concatenated per-theta src*64 tables
    __shared__ double rbufN[NWAVE*64], rbufD[NWAVE*64];  // rbufN reused as mpart
    __shared__ int    ridxB[NWAVE*64];
    __shared__ double mssum[64], msu[64];
    __shared__ int    mbS[64], mbT[64];

    const int tid = threadIdx.x;
    const int bt  = blockIdx.x;
    const int hh  = tid & 63;
    const int sg  = tid >> 6;           // 0..15
    const int grp = sg >> 3;            // 0: thetas 0-2, 1: thetas 3-4
    const int sw  = sg & 7;             // strip-pair index within group

    if (tid < 64) {
        sxy[tid] = x[bt * 64 + tid];
        sb1[tid] = b1[tid];
    } else if (tid >= 128 && tid < 208) {
        const int p = tid - 128;
        ypad[p] = (p >= 8 && p < 72) ? (double)y[bt * 64 + p - 8] : 0.0;
    }
    __syncthreads();

    if (tid < 64) {
        float acc = 0.0f;
        const float* w1r = W1 + tid * 64;
        for (int i = 0; i < 64; ++i) acc = fmaf(sxy[i], w1r[i], acc);
        acc += sb1[tid];
        sh[tid] = acc * (float)mask[bt * 64 + tid];
    }
    __syncthreads();

    // P table: P[o*64+h] = sh[h]*W2[o][h] + b2[o]
    for (int k = tid; k < 4096; k += NT) {
        P[k] = fmaf(sh[k & 63], W2[k], b2[k >> 6]);
    }
    // all 5 src tables (concatenated; offsets = cumsum of L: 0,51,108,172,242)
    if (tid < 318) {
        int rem = tid, t5 = 0;
        int L = 51;
        for (;;) {
            const double th = (t5 == 4) ? 1.2 : (0.8 + (double)t5 * ((1.2 - 0.8) / 4.0));
            L = (int)floor(64.0 * th);
            if (rem < L) break;
            rem -= L; ++t5;
        }
        const double rcp = 64.0 / (double)L;
        int sj = (int)floor((double)rem * rcp);
        if (sj > 63) sj = 63;
        ssrcAll[tid] = sj * 64;
    }
    __syncthreads();

    // ---- scan this group's thetas, no barriers ----
    double bN = -1.0, bD = 0.0; int bi = 0x7fffffff;
    const int t5beg = grp ? 3 : 0;
    const int t5end = grp ? 5 : 3;
    int off = grp ? 172 : 0;
    for (int t5 = t5beg; t5 < t5end; ++t5) {
        const double theta = (t5 == 4) ? 1.2 : (0.8 + (double)t5 * ((1.2 - 0.8) / 4.0));
        const int L = (int)floor(64.0 * theta);
        const int S = L + 63;
        const int* srcT = ssrcAll + off;
        off += L;

        #pragma unroll 2
        for (int pp = 0; pp < 2; ++pp) {
            const int s_first = 9 * (sw + 8 * pp);
            if (s_first >= S) continue;
            const int jstart = (s_first > 63) ? (s_first - 63) : 0;
            const int jmid   = (s_first < L - 1) ? s_first : (L - 1);
            const int jend   = (s_first + 8 < L - 1) ? (s_first + 8) : (L - 1);
            const int C      = 71 - s_first;      // ypad idx = j + C - k

            double d0=0,d1=0,d2=0,d3=0,d4=0,d5=0,d6=0,d7=0,d8=0,ssA=0;
            double ym1 = ypad[jstart + C - 1];
            double ym2 = ypad[jstart + C - 2];
            double ym3 = ypad[jstart + C - 3];
            double ym4 = ypad[jstart + C - 4];
            double ym5 = ypad[jstart + C - 5];
            double ym6 = ypad[jstart + C - 6];
            double ym7 = ypad[jstart + C - 7];
            double ym8 = ypad[jstart + C - 8];

            #pragma unroll 9
            for (int j = jstart; j <= jmid; ++j) {
                const double w  = (double)P[srcT[j] + hh];
                const double y0 = ypad[j + C];
                d0 = fma(w, y0,  d0); d1 = fma(w, ym1, d1); d2 = fma(w, ym2, d2);
                d3 = fma(w, ym3, d3); d4 = fma(w, ym4, d4); d5 = fma(w, ym5, d5);
                d6 = fma(w, ym6, d6); d7 = fma(w, ym7, d7); d8 = fma(w, ym8, d8);
                ssA = fma(w, w, ssA);
                ym8=ym7; ym7=ym6; ym6=ym5; ym5=ym4; ym4=ym3; ym3=ym2; ym2=ym1; ym1=y0;
            }
            #pragma unroll 9
            for (int j = jmid + 1; j <= jend; ++j) {
                const double w  = (double)P[srcT[j] + hh];
                const double y0 = ypad[j + C];
                d0 = fma(w, y0,  d0); d1 = fma(w, ym1, d1); d2 = fma(w, ym2, d2);
                d3 = fma(w, ym3, d3); d4 = fma(w, ym4, d4); d5 = fma(w, ym5, d5);
                d6 = fma(w, ym6, d6); d7 = fma(w, ym7, d7); d8 = fma(w, ym8, d8);
                ym8=ym7; ym7=ym6; ym6=ym5; ym5=ym4; ym4=ym3; ym3=ym2; ym2=ym1; ym1=y0;
            }

            const int kmax = (S - s_first < 9) ? (S - s_first) : 9;
            double ss = ssA;
            #define SSUP(kk) { \
                const int jh = s_first + kk; \
                const int jl = jh - 64; \
                if (jh <= L - 1) { const double w = (double)P[srcT[jh] + hh]; ss = fma(w,  w, ss); } \
                if (jl >= 0)     { const double w = (double)P[srcT[jl] + hh]; ss = fma(-w, w, ss); } }
            #define EVALK(kk, dk) { \
                double pn, pd; \
                if (ss > 0.0) { pn = dk * fabs(dk); pd = ss; } \
                else          { pn = 0.0;           pd = 1.0; } \
                if (pn * bD > bN * pd) { bN = pn; bD = pd; bi = (t5 << 8) | (s_first + kk); } }
            EVALK(0, d0)
            if (1 < kmax) { SSUP(1) EVALK(1, d1) }
            if (2 < kmax) { SSUP(2) EVALK(2, d2) }
            if (3 < kmax) { SSUP(3) EVALK(3, d3) }
            if (4 < kmax) { SSUP(4) EVALK(4, d4) }
            if (5 < kmax) { SSUP(5) EVALK(5, d5) }
            if (6 < kmax) { SSUP(6) EVALK(6, d6) }
            if (7 < kmax) { SSUP(7) EVALK(7, d7) }
            if (8 < kmax) { SSUP(8) EVALK(8, d8) }
            #undef SSUP
            #undef EVALK
        }
    }

    rbufN[sg * 64 + hh] = bN;
    rbufD[sg * 64 + hh] = bD;
    ridxB[sg * 64 + hh] = bi;
    __syncthreads();
    if (tid < 64) {
        // packed idx gives lexicographic (theta asc, s asc) tie-break;
        // exact ties have bitwise-equal (pn,pd) pairs.
        double mN = -1.0, mD = 0.0; int mi = 0x7fffffff;
        for (int g = 0; g < NWAVE; ++g) {
            const double vN = rbufN[g * 64 + tid];
            const double vD = rbufD[g * 64 + tid];
            const int    vi = ridxB[g * 64 + tid];
            const double a = vN * mD, b = mN * vD;
            if (a > b || (a == b && vi < mi)) { mN = vN; mD = vD; mi = vi; }
        }
        mbS[tid] = mi & 255;
        mbT[tid] = mi >> 8;
        sxy[tid] = y[bt * 64 + tid];       // sy for the loss
    }
    __syncthreads();

    double* mpart = rbufN;                 // reuse (barrier-separated)

    // ssum[i] = sum over h of chosen window value at element i (16 groups x 4 h)
    {
        const int g = sg, i = hh;
        double acc = 0.0;
        for (int q = 0; q < 4; ++q) {
            const int h = g * 4 + q;
            const int t = mbT[h];
            const double th2 = (t == 4) ? 1.2 : (0.8 + (double)t * ((1.2 - 0.8) / 4.0));
            const int Lh = (int)floor(64.0 * th2);
            const double rc = 64.0 / (double)Lh;
            const int jj = mbS[h] - 63 + i;
            if (jj >= 0 && jj < Lh) {
                int sj = (int)floor((double)jj * rc);
                if (sj > 63) sj = 63;
                // same bits as P[sj*64+h], via global (no LDS bank conflict)
                acc += (double)fmaf(sh[h], W2[sj * 64 + h], b2[sj]);
            }
        }
        mpart[g * 64 + i] = acc;
    }
    __syncthreads();
    if (tid < 64) {
        double s0 = 0.0;
        for (int g = 0; g < NWAVE; ++g) s0 += mpart[g * 64 + tid];
        mssum[tid] = s0;
    }
    __syncthreads();
    // u = W1 * ssum + 64*b1   (16 groups x 4 inner terms)
    {
        const int g = sg, i = hh, base = g * 4;
        double acc = 0.0;
        for (int q = 0; q < 4; ++q)
            acc += (double)W1[i * 64 + base + q] * mssum[base + q];
        mpart[g * 64 + i] = acc;
    }
    __syncthreads();
    if (tid < 64) {
        double s0 = 64.0 * (double)sb1[tid];
        for (int g = 0; g < NWAVE; ++g) s0 += mpart[g * 64 + tid];
        msu[tid] = s0;
    }
    __syncthreads();
    // v = W2 * u + 64*b2
    {
        const int g = sg, i = hh, base = g * 4;
        double acc = 0.0;
        for (int q = 0; q < 4; ++q)
            acc += (double)W2[i * 64 + base + q] * msu[base + q];
        mpart[g * 64 + i] = acc;
    }
    __syncthreads();
    if (tid < 64) {
        double v = 64.0 * (double)b2[tid];
        for (int g = 0; g < NWAVE; ++g) v += mpart[g * 64 + tid];
        const float outf = (float)v;
        out[1 + bt * 64 + tid] = outf;     // xf
        const float yv = sxy[tid];
        double pl = 0.0, pc = 0.0;
        if (yv != 0.0f) {
            const float d = outf - yv;
            pl = (double)(d * d);
            pc = 1.0;
        }
        for (int o = 32; o > 0; o >>= 1) {
            pl += __shfl_down(pl, o, 64);
            pc += __shfl_down(pc, o, 64);
        }
        if (tid == 0) { psum[bt] = pl; pcnt[bt] = pc; }
    }
}

__global__ __launch_bounds__(256) void finalize_loss(
    const double* __restrict__ psum, const double* __restrict__ pcnt,
    float* __restrict__ out)
{
    __shared__ double a[256], c[256];
    const int t = threadIdx.x;
    a[t] = psum[t];
    c[t] = pcnt[t];
    __syncthreads();
    for (int s = 128; s > 0; s >>= 1) {
        if (t < s) { a[t] += a[t + s]; c[t] += c[t + s]; }
        __syncthreads();
    }
    if (t == 0) out[0] = (float)(a[0] / c[0]);
}

extern "C" void kernel_launch(void* const* d_in, const int* in_sizes, int n_in,
                              void* d_out, int out_size, void* d_ws, size_t ws_size,
                              hipStream_t stream) {
    const float* x    = (const float*)d_in[0];
    const float* y    = (const float*)d_in[1];
    const int*   mask = (const int*)d_in[2];
    const float* W1   = (const float*)d_in[3];
    const float* b1   = (const float*)d_in[4];
    const float* W2   = (const float*)d_in[5];
    const float* b2   = (const float*)d_in[6];
    float* out = (float*)d_out;

    double* psum = (double*)d_ws;
    double* pcnt = psum + 256;

    argaug_all<<<256, NT, 0, stream>>>(x, y, mask, W1, b1, W2, b2,
                                       out, psum, pcnt);
    finalize_loss<<<1, 256, 0, stream>>>(psum, pcnt, out);
}

// Round 13
// 44.369 us; speedup vs baseline: 1.8460x; 1.0205x over previous
//
#include <hip/hip_runtime.h>
#include <math.h>

#define NT 1024
#define NWAVE 16
#define WROWS 318            // total window rows = 51+57+64+70+76
#define WPITCH 65            // +1 pad: epilogue per-lane-row gather conflict-free

// One block per bt (grid 256), 16 waves. Lane = channel hh. Wave group 0
// (waves 0-7) scans thetas {0,1,2}; group 1 scans {3,4}. Within a group,
// wave w owns strips {w, w+8} (9 shifts each) per theta -- perfectly
// balanced. All 5 thetas' window tables are materialized ONCE in LDS
// (wdAll[318][65] f32, widened exactly to f64 at use -- decision math
// bitwise-identical to prior passing rounds). Rows are consecutive in j,
// so scan ds_reads use offset immediates (no gather hop). Per-thread best
// carries packed idx = (t5<<8)|s -> lexicographic (theta asc, s asc) ties.
// Epilogue (window-sum via wdAll, 2 GEMVs, loss partials) in the same block.
__global__ __launch_bounds__(NT) void argaug_all(
    const float* __restrict__ x, const float* __restrict__ y,
    const int* __restrict__ mask,
    const float* __restrict__ W1, const float* __restrict__ b1,
    const float* __restrict__ W2, const float* __restrict__ b2,
    float* __restrict__ out, double* __restrict__ psum, double* __restrict__ pcnt)
{
    __shared__ float  wdAll[WROWS * WPITCH];   // 82680 B
    __shared__ double ypad[80];                // ypad[p] = y[p-8], p in [8,71], else 0
    __shared__ float  sxy[64], sh[64], sb1[64];
    __shared__ int2   ssrc[WROWS];             // {src*64, bits(b2[src])} per row
    __shared__ int    scum[5];                 // cumulative row offsets per theta
    __shared__ double rbufN[NWAVE*64], rbufD[NWAVE*64];  // rbufN reused as mpart
    __shared__ int    ridxB[NWAVE*64];
    __shared__ double mssum[64], msu[64];
    __shared__ int    mbS[64], mbT[64];

    const int tid = threadIdx.x;
    const int bt  = blockIdx.x;
    const int hh  = tid & 63;
    const int sg  = tid >> 6;           // 0..15
    const int grp = sg >> 3;            // 0: thetas 0-2, 1: thetas 3-4
    const int sw  = sg & 7;             // strip-pair index within group

    if (tid < 64) {
        sxy[tid] = x[bt * 64 + tid];
        sb1[tid] = b1[tid];
    } else if (tid >= 128 && tid < 208) {
        const int p = tid - 128;
        ypad[p] = (p >= 8 && p < 72) ? (double)y[bt * 64 + p - 8] : 0.0;
    } else if (tid >= 256 && tid < 256 + WROWS) {
        int rem = tid - 256, t5 = 0;
        int L = 51;
        for (;;) {
            const double th = (t5 == 4) ? 1.2 : (0.8 + (double)t5 * ((1.2 - 0.8) / 4.0));
            L = (int)floor(64.0 * th);
            if (rem < L) break;
            rem -= L; ++t5;
        }
        const double rcp = 64.0 / (double)L;
        int sj = (int)floor((double)rem * rcp);
        if (sj > 63) sj = 63;
        ssrc[tid - 256] = make_int2(sj * 64, __float_as_int(b2[sj]));
    } else if (tid >= 600 && tid < 605) {
        const int t = tid - 600;
        int off = 0;
        for (int u = 0; u < t; ++u) {
            const double th = (u == 4) ? 1.2 : (0.8 + (double)u * ((1.2 - 0.8) / 4.0));
            off += (int)floor(64.0 * th);
        }
        scum[t] = off;                   // {0,51,108,172,242}
    }
    __syncthreads();

    if (tid < 64) {
        // fc1: serial fmaf chain, bitwise-identical across all rounds
        float acc = 0.0f;
        const float* w1r = W1 + tid * 64;
        for (int i = 0; i < 64; ++i) acc = fmaf(sxy[i], w1r[i], acc);
        acc += sb1[tid];
        sh[tid] = acc * (float)mask[bt * 64 + tid];
    }
    __syncthreads();

    // Build all window rows: wd[row][h] = sh[h]*W2[src(row)][h] + b2[src(row)]
    for (int k = tid; k < WROWS * 64; k += NT) {
        const int row = k >> 6, h = k & 63;
        const int2 ow = ssrc[row];
        wdAll[row * WPITCH + h] = fmaf(sh[h], W2[ow.x + h], __int_as_float(ow.y));
    }
    __syncthreads();

    // ---- scan this group's thetas, no barriers ----
    double bN = -1.0, bD = 0.0; int bi = 0x7fffffff;
    const int t5beg = grp ? 3 : 0;
    const int t5end = grp ? 5 : 3;
    int off = grp ? 172 : 0;
    for (int t5 = t5beg; t5 < t5end; ++t5) {
        const double theta = (t5 == 4) ? 1.2 : (0.8 + (double)t5 * ((1.2 - 0.8) / 4.0));
        const int L = (int)floor(64.0 * theta);
        const int S = L + 63;
        const float* wrow = wdAll + off * WPITCH + hh;   // row j at wrow[j*WPITCH]
        off += L;

        #pragma unroll 2
        for (int pp = 0; pp < 2; ++pp) {
            const int s_first = 9 * (sw + 8 * pp);
            if (s_first >= S) continue;
            const int jstart = (s_first > 63) ? (s_first - 63) : 0;
            const int jmid   = (s_first < L - 1) ? s_first : (L - 1);
            const int jend   = (s_first + 8 < L - 1) ? (s_first + 8) : (L - 1);
            const int C      = 71 - s_first;      // ypad idx = j + C - k

            double d0=0,d1=0,d2=0,d3=0,d4=0,d5=0,d6=0,d7=0,d8=0,ssA=0;
            double ym1 = ypad[jstart + C - 1];
            double ym2 = ypad[jstart + C - 2];
            double ym3 = ypad[jstart + C - 3];
            double ym4 = ypad[jstart + C - 4];
            double ym5 = ypad[jstart + C - 5];
            double ym6 = ypad[jstart + C - 6];
            double ym7 = ypad[jstart + C - 7];
            double ym8 = ypad[jstart + C - 8];

            #pragma unroll 9
            for (int j = jstart; j <= jmid; ++j) {
                const double w  = (double)wrow[j * WPITCH];
                const double y0 = ypad[j + C];
                d0 = fma(w, y0,  d0); d1 = fma(w, ym1, d1); d2 = fma(w, ym2, d2);
                d3 = fma(w, ym3, d3); d4 = fma(w, ym4, d4); d5 = fma(w, ym5, d5);
                d6 = fma(w, ym6, d6); d7 = fma(w, ym7, d7); d8 = fma(w, ym8, d8);
                ssA = fma(w, w, ssA);
                ym8=ym7; ym7=ym6; ym6=ym5; ym5=ym4; ym4=ym3; ym3=ym2; ym2=ym1; ym1=y0;
            }
            #pragma unroll 9
            for (int j = jmid + 1; j <= jend; ++j) {
                const double w  = (double)wrow[j * WPITCH];
                const double y0 = ypad[j + C];
                d0 = fma(w, y0,  d0); d1 = fma(w, ym1, d1); d2 = fma(w, ym2, d2);
                d3 = fma(w, ym3, d3); d4 = fma(w, ym4, d4); d5 = fma(w, ym5, d5);
                d6 = fma(w, ym6, d6); d7 = fma(w, ym7, d7); d8 = fma(w, ym8, d8);
                ym8=ym7; ym7=ym6; ym6=ym5; ym5=ym4; ym4=ym3; ym3=ym2; ym2=ym1; ym1=y0;
            }

            const int kmax = (S - s_first < 9) ? (S - s_first) : 9;
            double ss = ssA;
            #define SSUP(kk) { \
                const int jh = s_first + kk; \
                const int jl = jh - 64; \
                if (jh <= L - 1) { const double w = (double)wrow[jh * WPITCH]; ss = fma(w,  w, ss); } \
                if (jl >= 0)     { const double w = (double)wrow[jl * WPITCH]; ss = fma(-w, w, ss); } }
            #define EVALK(kk, dk) { \
                double pn, pd; \
                if (ss > 0.0) { pn = dk * fabs(dk); pd = ss; } \
                else          { pn = 0.0;           pd = 1.0; } \
                if (pn * bD > bN * pd) { bN = pn; bD = pd; bi = (t5 << 8) | (s_first + kk); } }
            EVALK(0, d0)
            if (1 < kmax) { SSUP(1) EVALK(1, d1) }
            if (2 < kmax) { SSUP(2) EVALK(2, d2) }
            if (3 < kmax) { SSUP(3) EVALK(3, d3) }
            if (4 < kmax) { SSUP(4) EVALK(4, d4) }
            if (5 < kmax) { SSUP(5) EVALK(5, d5) }
            if (6 < kmax) { SSUP(6) EVALK(6, d6) }
            if (7 < kmax) { SSUP(7) EVALK(7, d7) }
            if (8 < kmax) { SSUP(8) EVALK(8, d8) }
            #undef SSUP
            #undef EVALK
        }
    }

    rbufN[sg * 64 + hh] = bN;
    rbufD[sg * 64 + hh] = bD;
    ridxB[sg * 64 + hh] = bi;
    __syncthreads();
    if (tid < 64) {
        // packed idx gives lexicographic (theta asc, s asc) tie-break;
        // exact ties have bitwise-equal (pn,pd) pairs. Same linear order
        // as prior rounds.
        double mN = -1.0, mD = 0.0; int mi = 0x7fffffff;
        for (int g = 0; g < NWAVE; ++g) {
            const double vN = rbufN[g * 64 + tid];
            const double vD = rbufD[g * 64 + tid];
            const int    vi = ridxB[g * 64 + tid];
            const double a = vN * mD, b = mN * vD;
            if (a > b || (a == b && vi < mi)) { mN = vN; mD = vD; mi = vi; }
        }
        mbS[tid] = mi & 255;
        mbT[tid] = mi >> 8;
        sxy[tid] = y[bt * 64 + tid];       // sy for the loss
    }
    __syncthreads();

    double* mpart = rbufN;                 // reuse (barrier-separated)

    // ssum[i] = sum over h of chosen window value at element i (16 grp x 4 h)
    // gathers from wdAll (same stored bits); padded pitch -> banks spread.
    {
        const int g = sg, i = hh;
        double acc = 0.0;
        for (int q = 0; q < 4; ++q) {
            const int h = g * 4 + q;
            const int t = mbT[h];
            const int Lh = scum[4] - scum[3] == 70 && false ? 0 :  // (no-op, keep simple)
                           ((t == 0) ? 51 : (t == 1) ? 57 : (t == 2) ? 64 : (t == 3) ? 70 : 76);
            const int jj = mbS[h] - 63 + i;
            if (jj >= 0 && jj < Lh) {
                acc += (double)wdAll[(scum[t] + jj) * WPITCH + h];
            }
        }
        mpart[g * 64 + i] = acc;
    }
    __syncthreads();
    if (tid < 64) {
        double s0 = 0.0;
        for (int g = 0; g < NWAVE; ++g) s0 += mpart[g * 64 + tid];
        mssum[tid] = s0;
    }
    __syncthreads();
    // u = W1 * ssum + 64*b1   (16 groups x 4 inner terms)
    {
        const int g = sg, i = hh, base = g * 4;
        double acc = 0.0;
        for (int q = 0; q < 4; ++q)
            acc += (double)W1[i * 64 + base + q] * mssum[base + q];
        mpart[g * 64 + i] = acc;
    }
    __syncthreads();
    if (tid < 64) {
        double s0 = 64.0 * (double)sb1[tid];
        for (int g = 0; g < NWAVE; ++g) s0 += mpart[g * 64 + tid];
        msu[tid] = s0;
    }
    __syncthreads();
    // v = W2 * u + 64*b2
    {
        const int g = sg, i = hh, base = g * 4;
        double acc = 0.0;
        for (int q = 0; q < 4; ++q)
            acc += (double)W2[i * 64 + base + q] * msu[base + q];
        mpart[g * 64 + i] = acc;
    }
    __syncthreads();
    if (tid < 64) {
        double v = 64.0 * (double)b2[tid];
        for (int g = 0; g < NWAVE; ++g) v += mpart[g * 64 + tid];
        const float outf = (float)v;
        out[1 + bt * 64 + tid] = outf;     // xf
        const float yv = sxy[tid];
        double pl = 0.0, pc = 0.0;
        if (yv != 0.0f) {
            const float d = outf - yv;
            pl = (double)(d * d);
            pc = 1.0;
        }
        for (int o = 32; o > 0; o >>= 1) {
            pl += __shfl_down(pl, o, 64);
            pc += __shfl_down(pc, o, 64);
        }
        if (tid == 0) { psum[bt] = pl; pcnt[bt] = pc; }
    }
}

__global__ __launch_bounds__(256) void finalize_loss(
    const double* __restrict__ psum, const double* __restrict__ pcnt,
    float* __restrict__ out)
{
    __shared__ double a[256], c[256];
    const int t = threadIdx.x;
    a[t] = psum[t];
    c[t] = pcnt[t];
    __syncthreads();
    for (int s = 128; s > 0; s >>= 1) {
        if (t < s) { a[t] += a[t + s]; c[t] += c[t + s]; }
        __syncthreads();
    }
    if (t == 0) out[0] = (float)(a[0] / c[0]);
}

extern "C" void kernel_launch(void* const* d_in, const int* in_sizes, int n_in,
                              void* d_out, int out_size, void* d_ws, size_t ws_size,
                              hipStream_t stream) {
    const float* x    = (const float*)d_in[0];
    const float* y    = (const float*)d_in[1];
    const int*   mask = (const int*)d_in[2];
    const float* W1   = (const float*)d_in[3];
    const float* b1   = (const float*)d_in[4];
    const float* W2   = (const float*)d_in[5];
    const float* b2   = (const float*)d_in[6];
    float* out = (float*)d_out;

    double* psum = (double*)d_ws;
    double* pcnt = psum + 256;

    argaug_all<<<256, NT, 0, stream>>>(x, y, mask, W1, b1, W2, b2,
                                       out, psum, pcnt);
    finalize_loss<<<1, 256, 0, stream>>>(psum, pcnt, out);
}

// Round 14
// 41.344 us; speedup vs baseline: 1.9811x; 1.0731x over previous
//
#include <hip/hip_runtime.h>
#include <math.h>

#define NT 1024
#define NWAVE 16
#define WROWS 318            // total window rows = 51+57+64+70+76
#define WPITCH 65            // +1 pad: epilogue per-lane-row gather conflict-free

// One block per bt (grid 256), 16 waves. Lane = channel hh. Wave group 0
// (waves 0-7) scans thetas {0,1,2}; group 1 scans {3,4}. Within a group,
// wave w owns strips {w, w+8} (9 shifts each) per theta -- perfectly
// balanced. All 5 thetas' window tables materialized once in LDS (f32).
// Hot dots/ss in f32 (ref computes sims in f32 too); candidate COMPARISON in
// f64 cross-multiplication of f32-origin values (24-bit mantissas -> 48-bit
// products, exact) -> deterministic exact ordering of the f32 sims, first-
// index tie rule preserved. Packed idx = (t5<<8)|s gives lexicographic ties.
// Epilogue (window-sum via wdAll, f64 GEMVs, loss partials) in-block.
__global__ __launch_bounds__(NT) void argaug_all(
    const float* __restrict__ x, const float* __restrict__ y,
    const int* __restrict__ mask,
    const float* __restrict__ W1, const float* __restrict__ b1,
    const float* __restrict__ W2, const float* __restrict__ b2,
    float* __restrict__ out, double* __restrict__ psum, double* __restrict__ pcnt)
{
    __shared__ float  wdAll[WROWS * WPITCH];   // 82680 B
    __shared__ float  ypad[80];                // ypad[p] = y[p-8], p in [8,71], else 0
    __shared__ float  sxy[64], sh[64], sb1[64];
    __shared__ int2   ssrc[WROWS];             // {src*64, bits(b2[src])} per row
    __shared__ int    scum[5];                 // cumulative row offsets per theta
    __shared__ double rbufN[NWAVE*64], rbufD[NWAVE*64];  // rbufN reused as mpart
    __shared__ int    ridxB[NWAVE*64];
    __shared__ double mssum[64], msu[64];
    __shared__ int    mbS[64], mbT[64];

    const int tid = threadIdx.x;
    const int bt  = blockIdx.x;
    const int hh  = tid & 63;
    const int sg  = tid >> 6;           // 0..15
    const int grp = sg >> 3;            // 0: thetas 0-2, 1: thetas 3-4
    const int sw  = sg & 7;             // strip-pair index within group

    if (tid < 64) {
        sxy[tid] = x[bt * 64 + tid];
        sb1[tid] = b1[tid];
    } else if (tid >= 128 && tid < 208) {
        const int p = tid - 128;
        ypad[p] = (p >= 8 && p < 72) ? y[bt * 64 + p - 8] : 0.0f;
    } else if (tid >= 256 && tid < 256 + WROWS) {
        int rem = tid - 256, t5 = 0;
        int L = 51;
        for (;;) {
            const double th = (t5 == 4) ? 1.2 : (0.8 + (double)t5 * ((1.2 - 0.8) / 4.0));
            L = (int)floor(64.0 * th);
            if (rem < L) break;
            rem -= L; ++t5;
        }
        const double rcp = 64.0 / (double)L;
        int sj = (int)floor((double)rem * rcp);
        if (sj > 63) sj = 63;
        ssrc[tid - 256] = make_int2(sj * 64, __float_as_int(b2[sj]));
    } else if (tid >= 600 && tid < 605) {
        const int t = tid - 600;
        int off = 0;
        for (int u = 0; u < t; ++u) {
            const double th = (u == 4) ? 1.2 : (0.8 + (double)u * ((1.2 - 0.8) / 4.0));
            off += (int)floor(64.0 * th);
        }
        scum[t] = off;                   // {0,51,108,172,242}
    }
    __syncthreads();

    if (tid < 64) {
        // fc1: serial fmaf chain, bitwise-identical across all rounds
        float acc = 0.0f;
        const float* w1r = W1 + tid * 64;
        for (int i = 0; i < 64; ++i) acc = fmaf(sxy[i], w1r[i], acc);
        acc += sb1[tid];
        sh[tid] = acc * (float)mask[bt * 64 + tid];
    }
    __syncthreads();

    // Build all window rows: wd[row][h] = sh[h]*W2[src(row)][h] + b2[src(row)]
    for (int k = tid; k < WROWS * 64; k += NT) {
        const int row = k >> 6, h = k & 63;
        const int2 ow = ssrc[row];
        wdAll[row * WPITCH + h] = fmaf(sh[h], W2[ow.x + h], __int_as_float(ow.y));
    }
    __syncthreads();

    // ---- scan this group's thetas (f32 dots), no barriers ----
    double bN = -1.0, bD = 0.0; int bi = 0x7fffffff;
    const int t5beg = grp ? 3 : 0;
    const int t5end = grp ? 5 : 3;
    int off = grp ? 172 : 0;
    for (int t5 = t5beg; t5 < t5end; ++t5) {
        const double theta = (t5 == 4) ? 1.2 : (0.8 + (double)t5 * ((1.2 - 0.8) / 4.0));
        const int L = (int)floor(64.0 * theta);
        const int S = L + 63;
        const float* wrow = wdAll + off * WPITCH + hh;   // row j at wrow[j*WPITCH]
        off += L;

        #pragma unroll 2
        for (int pp = 0; pp < 2; ++pp) {
            const int s_first = 9 * (sw + 8 * pp);
            if (s_first >= S) continue;
            const int jstart = (s_first > 63) ? (s_first - 63) : 0;
            const int jmid   = (s_first < L - 1) ? s_first : (L - 1);
            const int jend   = (s_first + 8 < L - 1) ? (s_first + 8) : (L - 1);
            const int C      = 71 - s_first;      // ypad idx = j + C - k

            float d0=0,d1=0,d2=0,d3=0,d4=0,d5=0,d6=0,d7=0,d8=0,ssA=0;
            float ym1 = ypad[jstart + C - 1];
            float ym2 = ypad[jstart + C - 2];
            float ym3 = ypad[jstart + C - 3];
            float ym4 = ypad[jstart + C - 4];
            float ym5 = ypad[jstart + C - 5];
            float ym6 = ypad[jstart + C - 6];
            float ym7 = ypad[jstart + C - 7];
            float ym8 = ypad[jstart + C - 8];

            #pragma unroll 9
            for (int j = jstart; j <= jmid; ++j) {
                const float w  = wrow[j * WPITCH];
                const float y0 = ypad[j + C];
                d0 = fmaf(w, y0,  d0); d1 = fmaf(w, ym1, d1); d2 = fmaf(w, ym2, d2);
                d3 = fmaf(w, ym3, d3); d4 = fmaf(w, ym4, d4); d5 = fmaf(w, ym5, d5);
                d6 = fmaf(w, ym6, d6); d7 = fmaf(w, ym7, d7); d8 = fmaf(w, ym8, d8);
                ssA = fmaf(w, w, ssA);
                ym8=ym7; ym7=ym6; ym6=ym5; ym5=ym4; ym4=ym3; ym3=ym2; ym2=ym1; ym1=y0;
            }
            #pragma unroll 9
            for (int j = jmid + 1; j <= jend; ++j) {
                const float w  = wrow[j * WPITCH];
                const float y0 = ypad[j + C];
                d0 = fmaf(w, y0,  d0); d1 = fmaf(w, ym1, d1); d2 = fmaf(w, ym2, d2);
                d3 = fmaf(w, ym3, d3); d4 = fmaf(w, ym4, d4); d5 = fmaf(w, ym5, d5);
                d6 = fmaf(w, ym6, d6); d7 = fmaf(w, ym7, d7); d8 = fmaf(w, ym8, d8);
                ym8=ym7; ym7=ym6; ym6=ym5; ym5=ym4; ym4=ym3; ym3=ym2; ym2=ym1; ym1=y0;
            }

            const int kmax = (S - s_first < 9) ? (S - s_first) : 9;
            float ss = ssA;
            #define SSUP(kk) { \
                const int jh = s_first + kk; \
                const int jl = jh - 64; \
                if (jh <= L - 1) { const float w = wrow[jh * WPITCH]; ss = fmaf(w,  w, ss); } \
                if (jl >= 0)     { const float w = wrow[jl * WPITCH]; ss = fmaf(-w, w, ss); } }
            #define EVALK(kk, dk) { \
                double pn, pd; \
                if (ss > 0.0f) { const double dd = (double)dk; pn = dd * fabs(dd); pd = (double)ss; } \
                else           { pn = 0.0; pd = 1.0; } \
                if (pn * bD > bN * pd) { bN = pn; bD = pd; bi = (t5 << 8) | (s_first + kk); } }
            EVALK(0, d0)
            if (1 < kmax) { SSUP(1) EVALK(1, d1) }
            if (2 < kmax) { SSUP(2) EVALK(2, d2) }
            if (3 < kmax) { SSUP(3) EVALK(3, d3) }
            if (4 < kmax) { SSUP(4) EVALK(4, d4) }
            if (5 < kmax) { SSUP(5) EVALK(5, d5) }
            if (6 < kmax) { SSUP(6) EVALK(6, d6) }
            if (7 < kmax) { SSUP(7) EVALK(7, d7) }
            if (8 < kmax) { SSUP(8) EVALK(8, d8) }
            #undef SSUP
            #undef EVALK
        }
    }

    rbufN[sg * 64 + hh] = bN;
    rbufD[sg * 64 + hh] = bD;
    ridxB[sg * 64 + hh] = bi;
    __syncthreads();
    if (tid < 64) {
        // exact f64 cross-mult over f32-origin pairs: true ordering of the
        // f32 sims; ties (bitwise-equal pairs) -> smaller packed idx.
        double mN = -1.0, mD = 0.0; int mi = 0x7fffffff;
        for (int g = 0; g < NWAVE; ++g) {
            const double vN = rbufN[g * 64 + tid];
            const double vD = rbufD[g * 64 + tid];
            const int    vi = ridxB[g * 64 + tid];
            const double a = vN * mD, b = mN * vD;
            if (a > b || (a == b && vi < mi)) { mN = vN; mD = vD; mi = vi; }
        }
        mbS[tid] = mi & 255;
        mbT[tid] = mi >> 8;
        sxy[tid] = y[bt * 64 + tid];       // sy for the loss
    }
    __syncthreads();

    double* mpart = rbufN;                 // reuse (barrier-separated)

    // ssum[i] = sum over h of chosen window value at element i (16 grp x 4 h)
    {
        const int g = sg, i = hh;
        double acc = 0.0;
        for (int q = 0; q < 4; ++q) {
            const int h = g * 4 + q;
            const int t = mbT[h];
            const int Lh = (t == 0) ? 51 : (t == 1) ? 57 : (t == 2) ? 64 : (t == 3) ? 70 : 76;
            const int jj = mbS[h] - 63 + i;
            if (jj >= 0 && jj < Lh) {
                acc += (double)wdAll[(scum[t] + jj) * WPITCH + h];
            }
        }
        mpart[g * 64 + i] = acc;
    }
    __syncthreads();
    if (tid < 64) {
        double s0 = 0.0;
        for (int g = 0; g < NWAVE; ++g) s0 += mpart[g * 64 + tid];
        mssum[tid] = s0;
    }
    __syncthreads();
    // u = W1 * ssum + 64*b1   (16 groups x 4 inner terms)
    {
        const int g = sg, i = hh, base = g * 4;
        double acc = 0.0;
        for (int q = 0; q < 4; ++q)
            acc += (double)W1[i * 64 + base + q] * mssum[base + q];
        mpart[g * 64 + i] = acc;
    }
    __syncthreads();
    if (tid < 64) {
        double s0 = 64.0 * (double)sb1[tid];
        for (int g = 0; g < NWAVE; ++g) s0 += mpart[g * 64 + tid];
        msu[tid] = s0;
    }
    __syncthreads();
    // v = W2 * u + 64*b2
    {
        const int g = sg, i = hh, base = g * 4;
        double acc = 0.0;
        for (int q = 0; q < 4; ++q)
            acc += (double)W2[i * 64 + base + q] * msu[base + q];
        mpart[g * 64 + i] = acc;
    }
    __syncthreads();
    if (tid < 64) {
        double v = 64.0 * (double)b2[tid];
        for (int g = 0; g < NWAVE; ++g) v += mpart[g * 64 + tid];
        const float outf = (float)v;
        out[1 + bt * 64 + tid] = outf;     // xf
        const float yv = sxy[tid];
        double pl = 0.0, pc = 0.0;
        if (yv != 0.0f) {
            const float d = outf - yv;
            pl = (double)(d * d);
            pc = 1.0;
        }
        for (int o = 32; o > 0; o >>= 1) {
            pl += __shfl_down(pl, o, 64);
            pc += __shfl_down(pc, o, 64);
        }
        if (tid == 0) { psum[bt] = pl; pcnt[bt] = pc; }
    }
}

__global__ __launch_bounds__(256) void finalize_loss(
    const double* __restrict__ psum, const double* __restrict__ pcnt,
    float* __restrict__ out)
{
    __shared__ double a[256], c[256];
    const int t = threadIdx.x;
    a[t] = psum[t];
    c[t] = pcnt[t];
    __syncthreads();
    for (int s = 128; s > 0; s >>= 1) {
        if (t < s) { a[t] += a[t + s]; c[t] += c[t + s]; }
        __syncthreads();
    }
    if (t == 0) out[0] = (float)(a[0] / c[0]);
}

extern "C" void kernel_launch(void* const* d_in, const int* in_sizes, int n_in,
                              void* d_out, int out_size, void* d_ws, size_t ws_size,
                              hipStream_t stream) {
    const float* x    = (const float*)d_in[0];
    const float* y    = (const float*)d_in[1];
    const int*   mask = (const int*)d_in[2];
    const float* W1   = (const float*)d_in[3];
    const float* b1   = (const float*)d_in[4];
    const float* W2   = (const float*)d_in[5];
    const float* b2   = (const float*)d_in[6];
    float* out = (float*)d_out;

    double* psum = (double*)d_ws;
    double* pcnt = psum + 256;

    argaug_all<<<256, NT, 0, stream>>>(x, y, mask, W1, b1, W2, b2,
                                       out, psum, pcnt);
    finalize_loss<<<1, 256, 0, stream>>>(psum, pcnt, out);
}